// Round 2
// baseline (154.465 us; speedup 1.0000x reference)
//
#include <hip/hip_runtime.h>
#include <hip/hip_cooperative_groups.h>

namespace cg = cooperative_groups;

// Problem constants (B,K,S1,S2,S3) = (4,8,64,64,64)
#define SB 4
#define SK 8
#define KM1 7
#define NBK (SB * KM1)
#define NVOX (64 * 64 * 64)
#define NV4 (NVOX / 4)       // 65536 float4 per (b,k) plane
#define TILES 256            // tiles per b; tile = 256 float4 = 1024 voxels
#define GSTEP (2.0f / 63.0f)

// ===========================================================================
// Fused single-pass cooperative kernel.
// Block g = (b, tile).  Phase 1: load 7 k-planes' float4 for this tile into
// registers, block-reduce partial moments (s, gy-weighted, gz-weighted; the
// gx weight is block-constant and folded in phase 2), write 21 floats to ws.
// grid.sync().  Phase 2: every block reduces its b's 21x256 partials (L2-hot)
// and builds the 7 affine coefficient sets M=R-I, d=p-Rp+t in LDS.
// Phase 3: out = sum_k m_k * (M_k g + d_k) using the register-resident mask.
// ws layout: ws[(b*21 + pair)*256 + tile], pair = k*3 + {s,my,mz}
// ===========================================================================
__global__ __launch_bounds__(256, 4) void fused_kernel(
        const float* __restrict__ mask, const float* __restrict__ trans,
        const float* __restrict__ rot, float* __restrict__ out,
        float* __restrict__ ws) {
    cg::grid_group gridg = cg::this_grid();
    const int b = blockIdx.x >> 8;
    const int tile = blockIdx.x & 255;
    const int tid = threadIdx.x;

    // Analytic grid coords for this thread's 4 voxels.
    // v = (tile*256 + tid)*4 ; i = tile>>2 (block-const), j, l per thread.
    const float gx = -1.0f + (float)(tile >> 2) * GSTEP;
    const int j = ((tile << 4) + (tid >> 4)) & 63;
    const float gy = -1.0f + (float)j * GSTEP;
    const float gz0 = -1.0f + (float)((tid & 15) << 2) * GSTEP;
    const float gz1 = gz0 + GSTEP, gz2 = gz0 + 2.f * GSTEP, gz3 = gz0 + 3.f * GSTEP;

    const int v4 = tile * 256 + tid;
    const float4* m4 = (const float4*)mask + (size_t)b * SK * NV4 + v4;
    float4 m[KM1];
#pragma unroll
    for (int k = 0; k < KM1; ++k) m[k] = m4[(size_t)k * NV4];

    // ---- Phase 1: per-thread partial moments, block reduce ----
    float s[KM1], my[KM1], mz[KM1];
#pragma unroll
    for (int k = 0; k < KM1; ++k) {
        const float4 mm = m[k];
        const float ms = mm.x + mm.y + mm.z + mm.w;
        s[k] = ms;
        my[k] = gy * ms;
        mz[k] = fmaf(gz0, mm.x, fmaf(gz1, mm.y, fmaf(gz2, mm.z, gz3 * mm.w)));
    }
#pragma unroll
    for (int off = 32; off > 0; off >>= 1) {
#pragma unroll
        for (int k = 0; k < KM1; ++k) {
            s[k]  += __shfl_down(s[k],  off, 64);
            my[k] += __shfl_down(my[k], off, 64);
            mz[k] += __shfl_down(mz[k], off, 64);
        }
    }
    __shared__ float red[4][21];
    const int wave = tid >> 6, lane = tid & 63;
    if (lane == 0) {
#pragma unroll
        for (int k = 0; k < KM1; ++k) {
            red[wave][k * 3 + 0] = s[k];
            red[wave][k * 3 + 1] = my[k];
            red[wave][k * 3 + 2] = mz[k];
        }
    }
    __syncthreads();
    if (tid < 21) {
        const float v = red[0][tid] + red[1][tid] + red[2][tid] + red[3][tid];
        ws[((size_t)b * 21 + tid) * TILES + tile] = v;
    }
    gridg.sync();

    // ---- Phase 2: reduce 256 tiles per (b,pair); build coefficients ----
    __shared__ float r1[21][8];
    __shared__ float r2[KM1][8];      // gx-weighted sums (only for mom==0)
    __shared__ float momf[KM1][4];    // {S, MX, MY, MZ}
    __shared__ float cf[KM1 * 12];
    if (tid < 168) {
        const int pair = tid >> 3, sub = tid & 7;
        const int mom = pair - (pair / 3) * 3;
        const float* wsp = ws + ((size_t)b * 21 + pair) * TILES + sub * 32;
        float sum = 0.f, gxs = 0.f;
#pragma unroll
        for (int ii = 0; ii < 32; ++ii) {
            const float x = wsp[ii];
            sum += x;
            const int tl = sub * 32 + ii;
            gxs = fmaf(-1.0f + (float)(tl >> 2) * GSTEP, x, gxs);
        }
        r1[pair][sub] = sum;
        if (mom == 0) r2[pair / 3][sub] = gxs;
    }
    __syncthreads();
    if (tid < 21) {
        const int k = tid / 3, mom = tid - k * 3;
        float t1 = 0.f;
#pragma unroll
        for (int sub = 0; sub < 8; ++sub) t1 += r1[tid][sub];
        if (mom == 0) {
            float t2 = 0.f;
#pragma unroll
            for (int sub = 0; sub < 8; ++sub) t2 += r2[k][sub];
            momf[k][0] = t1;  // S
            momf[k][1] = t2;  // MX
        } else if (mom == 1) {
            momf[k][2] = t1;  // MY
        } else {
            momf[k][3] = t1;  // MZ
        }
    }
    __syncthreads();
    if (tid < KM1) {
        const int k = tid;
        const int base = b * KM1 + k;
        const float S = momf[k][0];
        const float p0 = momf[k][1] / S;
        const float p1 = momf[k][2] / S;
        const float p2 = momf[k][3] / S;
        const float* R = rot + base * 9;
        const float* tv = trans + base * 3;
        float* c = cf + k * 12;
        c[0] = R[0] - 1.0f; c[1] = R[1];        c[2] = R[2];
        c[3] = R[3];        c[4] = R[4] - 1.0f; c[5] = R[5];
        c[6] = R[6];        c[7] = R[7];        c[8] = R[8] - 1.0f;
        c[9]  = p0 - (R[0] * p0 + R[1] * p1 + R[2] * p2) + tv[0];
        c[10] = p1 - (R[3] * p0 + R[4] * p1 + R[5] * p2) + tv[1];
        c[11] = p2 - (R[6] * p0 + R[7] * p1 + R[8] * p2) + tv[2];
    }
    __syncthreads();

    // ---- Phase 3: output from register-resident mask ----
    float4 o0 = {0, 0, 0, 0}, o1 = {0, 0, 0, 0}, o2 = {0, 0, 0, 0};
#pragma unroll
    for (int k = 0; k < KM1; ++k) {
        const float4 mm = m[k];
        const float* c = cf + k * 12;
        const float tx = c[0] * gx + c[1] * gy + c[9];
        const float ty = c[3] * gx + c[4] * gy + c[10];
        const float tz = c[6] * gx + c[7] * gy + c[11];
        o0.x += mm.x * fmaf(c[2], gz0, tx);
        o0.y += mm.y * fmaf(c[2], gz1, tx);
        o0.z += mm.z * fmaf(c[2], gz2, tx);
        o0.w += mm.w * fmaf(c[2], gz3, tx);
        o1.x += mm.x * fmaf(c[5], gz0, ty);
        o1.y += mm.y * fmaf(c[5], gz1, ty);
        o1.z += mm.z * fmaf(c[5], gz2, ty);
        o1.w += mm.w * fmaf(c[5], gz3, ty);
        o2.x += mm.x * fmaf(c[8], gz0, tz);
        o2.y += mm.y * fmaf(c[8], gz1, tz);
        o2.z += mm.z * fmaf(c[8], gz2, tz);
        o2.w += mm.w * fmaf(c[8], gz3, tz);
    }
    float4* out4 = (float4*)out;
    out4[((size_t)b * 3 + 0) * NV4 + v4] = o0;
    out4[((size_t)b * 3 + 1) * NV4 + v4] = o1;
    out4[((size_t)b * 3 + 2) * NV4 + v4] = o2;
}

// ===========================================================================
// Fallback path (round-1 proven kernels) in case cooperative launch is
// rejected under graph capture.
// ===========================================================================
#define CHUNKS 16

__global__ void zero_ws_kernel(float* __restrict__ ws) {
    int t = threadIdx.x;
    if (t < NBK * 4) ws[t] = 0.0f;
}

__global__ __launch_bounds__(256) void moments_kernel(
        const float* __restrict__ mask, float* __restrict__ mom) {
    const int bk = blockIdx.x / CHUNKS;
    const int chunk = blockIdx.x % CHUNKS;
    const int b = bk / KM1;
    const int k = bk % KM1;
    const float4* m4 = (const float4*)(mask + (size_t)(b * SK + k) * NVOX);
    float s = 0.f, mx = 0.f, my = 0.f, mz = 0.f;
    const int base = chunk * (NV4 / CHUNKS) + threadIdx.x;
#pragma unroll
    for (int it = 0; it < (NV4 / CHUNKS) / 256; ++it) {
        const int v4 = base + it * 256;
        const float4 m = m4[v4];
        const int v = v4 << 2;
        const float gx = -1.0f + (v >> 12) * GSTEP;
        const float gy = -1.0f + ((v >> 6) & 63) * GSTEP;
        const float gz = -1.0f + (v & 63) * GSTEP;
        const float msum = m.x + m.y + m.z + m.w;
        s += msum; mx += gx * msum; my += gy * msum;
        mz += gz * m.x + (gz + GSTEP) * m.y + (gz + 2.f * GSTEP) * m.z
            + (gz + 3.f * GSTEP) * m.w;
    }
#pragma unroll
    for (int off = 32; off > 0; off >>= 1) {
        s += __shfl_down(s, off, 64);   mx += __shfl_down(mx, off, 64);
        my += __shfl_down(my, off, 64); mz += __shfl_down(mz, off, 64);
    }
    __shared__ float red[4][4];
    const int wave = threadIdx.x >> 6, lane = threadIdx.x & 63;
    if (lane == 0) { red[wave][0]=s; red[wave][1]=mx; red[wave][2]=my; red[wave][3]=mz; }
    __syncthreads();
    if (threadIdx.x == 0) {
        float a0=0,a1=0,a2=0,a3=0;
#pragma unroll
        for (int w = 0; w < 4; ++w) { a0+=red[w][0]; a1+=red[w][1]; a2+=red[w][2]; a3+=red[w][3]; }
        atomicAdd(&mom[bk*4+0], a0); atomicAdd(&mom[bk*4+1], a1);
        atomicAdd(&mom[bk*4+2], a2); atomicAdd(&mom[bk*4+3], a3);
    }
}

__global__ void coeff_kernel(const float* __restrict__ mom,
                             const float* __restrict__ trans,
                             const float* __restrict__ rot,
                             float* __restrict__ coef) {
    const int t = threadIdx.x;
    if (t >= NBK) return;
    const float s = mom[t*4+0];
    const float p0 = mom[t*4+1]/s, p1 = mom[t*4+2]/s, p2 = mom[t*4+3]/s;
    const float* R = rot + t*9;
    const float* tv = trans + t*3;
    float* c = coef + t*12;
    c[0]=R[0]-1.f; c[1]=R[1]; c[2]=R[2];
    c[3]=R[3]; c[4]=R[4]-1.f; c[5]=R[5];
    c[6]=R[6]; c[7]=R[7]; c[8]=R[8]-1.f;
    c[9]  = p0-(R[0]*p0+R[1]*p1+R[2]*p2)+tv[0];
    c[10] = p1-(R[3]*p0+R[4]*p1+R[5]*p2)+tv[1];
    c[11] = p2-(R[6]*p0+R[7]*p1+R[8]*p2)+tv[2];
}

__global__ __launch_bounds__(256) void output_kernel(
        const float* __restrict__ mask, const float* __restrict__ coef,
        float* __restrict__ out) {
    const int b = blockIdx.y;
    __shared__ float cf[KM1 * 12];
    if (threadIdx.x < KM1 * 12) cf[threadIdx.x] = coef[b * KM1 * 12 + threadIdx.x];
    __syncthreads();
    const int v4 = blockIdx.x * 256 + threadIdx.x;
    const int v = v4 << 2;
    const float gx = -1.0f + (v >> 12) * GSTEP;
    const float gy = -1.0f + ((v >> 6) & 63) * GSTEP;
    const float gz0 = -1.0f + (v & 63) * GSTEP;
    const float gz1 = gz0+GSTEP, gz2 = gz0+2.f*GSTEP, gz3 = gz0+3.f*GSTEP;
    float4 o0={0,0,0,0}, o1={0,0,0,0}, o2={0,0,0,0};
    const float4* m4 = (const float4*)mask + (size_t)b * SK * NV4 + v4;
#pragma unroll
    for (int k = 0; k < KM1; ++k) {
        const float4 m = m4[k * NV4];
        const float* c = cf + k * 12;
        const float tx = c[0]*gx + c[1]*gy + c[9];
        const float ty = c[3]*gx + c[4]*gy + c[10];
        const float tz = c[6]*gx + c[7]*gy + c[11];
        o0.x += m.x*fmaf(c[2],gz0,tx); o0.y += m.y*fmaf(c[2],gz1,tx);
        o0.z += m.z*fmaf(c[2],gz2,tx); o0.w += m.w*fmaf(c[2],gz3,tx);
        o1.x += m.x*fmaf(c[5],gz0,ty); o1.y += m.y*fmaf(c[5],gz1,ty);
        o1.z += m.z*fmaf(c[5],gz2,ty); o1.w += m.w*fmaf(c[5],gz3,ty);
        o2.x += m.x*fmaf(c[8],gz0,tz); o2.y += m.y*fmaf(c[8],gz1,tz);
        o2.z += m.z*fmaf(c[8],gz2,tz); o2.w += m.w*fmaf(c[8],gz3,tz);
    }
    float4* out4 = (float4*)out;
    out4[((size_t)b*3+0)*NV4 + v4] = o0;
    out4[((size_t)b*3+1)*NV4 + v4] = o1;
    out4[((size_t)b*3+2)*NV4 + v4] = o2;
}

extern "C" void kernel_launch(void* const* d_in, const int* in_sizes, int n_in,
                              void* d_out, int out_size, void* d_ws, size_t ws_size,
                              hipStream_t stream) {
    const float* mask  = (const float*)d_in[0];
    const float* trans = (const float*)d_in[1];
    const float* rot   = (const float*)d_in[2];
    float* out = (float*)d_out;
    float* ws  = (float*)d_ws;

    void* args[] = {(void*)&mask, (void*)&trans, (void*)&rot, (void*)&out, (void*)&ws};
    hipError_t err = hipLaunchCooperativeKernel((const void*)fused_kernel,
                                                dim3(SB * TILES), dim3(256),
                                                args, 0, stream);
    if (err != hipSuccess) {
        // Fallback: proven 4-kernel path (mask read twice).
        float* mom  = ws;
        float* coef = ws + 128;
        zero_ws_kernel<<<1, 128, 0, stream>>>(mom);
        moments_kernel<<<NBK * CHUNKS, 256, 0, stream>>>(mask, mom);
        coeff_kernel<<<1, 32, 0, stream>>>(mom, trans, rot, coef);
        output_kernel<<<dim3(NV4 / 256, SB), 256, 0, stream>>>(mask, coef, out);
    }
}

// Round 3
// 87.624 us; speedup vs baseline: 1.7628x; 1.7628x over previous
//
#include <hip/hip_runtime.h>

// Problem constants (B,K,S1,S2,S3) = (4,8,64,64,64)
#define SB 4
#define SK 8
#define KM1 7
#define NBK (SB * KM1)       // 28
#define NVOX (64 * 64 * 64)
#define NV4 (NVOX / 4)       // 65536 float4 per (b,k) plane
#define CHUNKS 16            // partial-reduction blocks per (b,k)
#define GSTEP (2.0f / 63.0f)

// ws layout (floats): ws[bk*64 + chunk*4 + m], m = {S, MX, MY, MZ}
// Written non-atomically by moments_kernel (one block per (bk,chunk));
// reduced redundantly by every output block (its own b only). Kernel-launch
// boundary provides the cross-XCD visibility.

__global__ __launch_bounds__(256) void moments_kernel(
        const float* __restrict__ mask, float* __restrict__ ws) {
    const int bk = blockIdx.x / CHUNKS;
    const int chunk = blockIdx.x % CHUNKS;
    const int b = bk / KM1;
    const int k = bk % KM1;
    const float4* m4 = (const float4*)(mask + (size_t)(b * SK + k) * NVOX);

    float s = 0.f, mx = 0.f, my = 0.f, mz = 0.f;
    const int base = chunk * (NV4 / CHUNKS) + threadIdx.x;
#pragma unroll
    for (int it = 0; it < (NV4 / CHUNKS) / 256; ++it) {
        const int v4 = base + it * 256;
        const float4 m = m4[v4];
        const int v = v4 << 2;
        const float gx = -1.0f + (float)(v >> 12) * GSTEP;
        const float gy = -1.0f + (float)((v >> 6) & 63) * GSTEP;
        const float gz = -1.0f + (float)(v & 63) * GSTEP;
        const float msum = m.x + m.y + m.z + m.w;
        s  += msum;
        mx += gx * msum;
        my += gy * msum;
        mz += fmaf(gz, m.x, fmaf(gz + GSTEP, m.y,
              fmaf(gz + 2.f * GSTEP, m.z, (gz + 3.f * GSTEP) * m.w)));
    }
    // 64-lane butterfly, then cross-wave via LDS
#pragma unroll
    for (int off = 32; off > 0; off >>= 1) {
        s  += __shfl_down(s,  off, 64);
        mx += __shfl_down(mx, off, 64);
        my += __shfl_down(my, off, 64);
        mz += __shfl_down(mz, off, 64);
    }
    __shared__ float red[4][4];
    const int wave = threadIdx.x >> 6, lane = threadIdx.x & 63;
    if (lane == 0) {
        red[wave][0] = s; red[wave][1] = mx; red[wave][2] = my; red[wave][3] = mz;
    }
    __syncthreads();
    if (threadIdx.x == 0) {
        float a0 = 0.f, a1 = 0.f, a2 = 0.f, a3 = 0.f;
#pragma unroll
        for (int w = 0; w < 4; ++w) {
            a0 += red[w][0]; a1 += red[w][1]; a2 += red[w][2]; a3 += red[w][3];
        }
        float* p = ws + (size_t)bk * (CHUNKS * 4) + chunk * 4;
        p[0] = a0; p[1] = a1; p[2] = a2; p[3] = a3;
    }
}

// out[b,c,v] = sum_k mask[b,k,v] * (M_k g_v + d_k)_c, with per-block
// redundant coefficient construction from the ws partials (L2-broadcast).
__global__ __launch_bounds__(256) void output_kernel(
        const float* __restrict__ mask, const float* __restrict__ ws,
        const float* __restrict__ trans, const float* __restrict__ rot,
        float* __restrict__ out) {
    const int b = blockIdx.y;
    const int tid = threadIdx.x;

    __shared__ float momf[KM1][4];
    __shared__ float cf[KM1 * 12];
    if (tid < KM1 * 4) {
        const int k = tid >> 2, m = tid & 3;
        const float* p = ws + (size_t)(b * KM1 + k) * (CHUNKS * 4) + m;
        float acc = 0.f;
#pragma unroll
        for (int c = 0; c < CHUNKS; ++c) acc += p[c * 4];
        momf[k][m] = acc;
    }
    __syncthreads();
    if (tid < KM1) {
        const int k = tid;
        const int base = b * KM1 + k;
        const float S  = momf[k][0];
        const float p0 = momf[k][1] / S;
        const float p1 = momf[k][2] / S;
        const float p2 = momf[k][3] / S;
        const float* R  = rot + base * 9;
        const float* tv = trans + base * 3;
        float* c = cf + k * 12;
        c[0] = R[0] - 1.0f; c[1] = R[1];        c[2] = R[2];
        c[3] = R[3];        c[4] = R[4] - 1.0f; c[5] = R[5];
        c[6] = R[6];        c[7] = R[7];        c[8] = R[8] - 1.0f;
        c[9]  = p0 - (R[0] * p0 + R[1] * p1 + R[2] * p2) + tv[0];
        c[10] = p1 - (R[3] * p0 + R[4] * p1 + R[5] * p2) + tv[1];
        c[11] = p2 - (R[6] * p0 + R[7] * p1 + R[8] * p2) + tv[2];
    }
    __syncthreads();

    const int v4 = blockIdx.x * 256 + tid;
    const int v = v4 << 2;
    const float gx  = -1.0f + (float)(v >> 12) * GSTEP;
    const float gy  = -1.0f + (float)((v >> 6) & 63) * GSTEP;
    const float gz0 = -1.0f + (float)(v & 63) * GSTEP;
    const float gz1 = gz0 + GSTEP, gz2 = gz0 + 2.f * GSTEP, gz3 = gz0 + 3.f * GSTEP;

    float4 o0 = {0, 0, 0, 0}, o1 = {0, 0, 0, 0}, o2 = {0, 0, 0, 0};
    const float4* m4 = (const float4*)mask + (size_t)b * SK * NV4 + v4;
#pragma unroll
    for (int k = 0; k < KM1; ++k) {
        const float4 m = m4[(size_t)k * NV4];
        const float* c = cf + k * 12;
        const float tx = fmaf(c[0], gx, fmaf(c[1], gy, c[9]));
        const float ty = fmaf(c[3], gx, fmaf(c[4], gy, c[10]));
        const float tz = fmaf(c[6], gx, fmaf(c[7], gy, c[11]));
        o0.x += m.x * fmaf(c[2], gz0, tx);
        o0.y += m.y * fmaf(c[2], gz1, tx);
        o0.z += m.z * fmaf(c[2], gz2, tx);
        o0.w += m.w * fmaf(c[2], gz3, tx);
        o1.x += m.x * fmaf(c[5], gz0, ty);
        o1.y += m.y * fmaf(c[5], gz1, ty);
        o1.z += m.z * fmaf(c[5], gz2, ty);
        o1.w += m.w * fmaf(c[5], gz3, ty);
        o2.x += m.x * fmaf(c[8], gz0, tz);
        o2.y += m.y * fmaf(c[8], gz1, tz);
        o2.z += m.z * fmaf(c[8], gz2, tz);
        o2.w += m.w * fmaf(c[8], gz3, tz);
    }
    float4* out4 = (float4*)out;
    out4[((size_t)b * 3 + 0) * NV4 + v4] = o0;
    out4[((size_t)b * 3 + 1) * NV4 + v4] = o1;
    out4[((size_t)b * 3 + 2) * NV4 + v4] = o2;
}

extern "C" void kernel_launch(void* const* d_in, const int* in_sizes, int n_in,
                              void* d_out, int out_size, void* d_ws, size_t ws_size,
                              hipStream_t stream) {
    const float* mask  = (const float*)d_in[0]; // (4,8,64,64,64)
    const float* trans = (const float*)d_in[1]; // (4,7,3)
    const float* rot   = (const float*)d_in[2]; // (4,7,3,3)
    float* out = (float*)d_out;                 // (4,3,64,64,64)
    float* ws  = (float*)d_ws;                  // 28*64 floats of partials

    moments_kernel<<<NBK * CHUNKS, 256, 0, stream>>>(mask, ws);
    output_kernel<<<dim3(NV4 / 256, SB), 256, 0, stream>>>(mask, ws, trans, rot, out);
}

// Round 5
// 86.738 us; speedup vs baseline: 1.7808x; 1.0102x over previous
//
#include <hip/hip_runtime.h>

// Problem constants (B,K,S1,S2,S3) = (4,8,64,64,64)
#define SB 4
#define SK 8
#define KM1 7
#define NBK (SB * KM1)       // 28
#define NVOX (64 * 64 * 64)
#define NV4 (NVOX / 4)       // 65536 float4 per (b,k) plane
#define CHUNKS 32            // partial-reduction blocks per (b,k) (896 blocks)
#define GSTEP (2.0f / 63.0f)

typedef __attribute__((ext_vector_type(4))) float nt_float4;

// ws layout (floats): ws[bk*CHUNKS*4 + chunk*4 + m], m = {S, MX, MY, MZ}
// Written non-atomically by moments_kernel (one block per (bk,chunk));
// reduced redundantly by every output block (its own b only). Kernel-launch
// boundary provides the cross-XCD visibility.

__global__ __launch_bounds__(256) void moments_kernel(
        const float* __restrict__ mask, float* __restrict__ ws) {
    const int bk = blockIdx.x / CHUNKS;
    const int chunk = blockIdx.x % CHUNKS;
    const int b = bk / KM1;
    const int k = bk % KM1;
    const float4* m4 = (const float4*)(mask + (size_t)(b * SK + k) * NVOX);

    float s = 0.f, mx = 0.f, my = 0.f, mz = 0.f;
    const int base = chunk * (NV4 / CHUNKS) + threadIdx.x;
#pragma unroll
    for (int it = 0; it < (NV4 / CHUNKS) / 256; ++it) {
        const int v4 = base + it * 256;
        const float4 m = m4[v4];
        const int v = v4 << 2;
        const float gx = -1.0f + (float)(v >> 12) * GSTEP;
        const float gy = -1.0f + (float)((v >> 6) & 63) * GSTEP;
        const float gz = -1.0f + (float)(v & 63) * GSTEP;
        const float msum = m.x + m.y + m.z + m.w;
        s  += msum;
        mx += gx * msum;
        my += gy * msum;
        mz += fmaf(gz, m.x, fmaf(gz + GSTEP, m.y,
              fmaf(gz + 2.f * GSTEP, m.z, (gz + 3.f * GSTEP) * m.w)));
    }
    // 64-lane butterfly, then cross-wave via LDS
#pragma unroll
    for (int off = 32; off > 0; off >>= 1) {
        s  += __shfl_down(s,  off, 64);
        mx += __shfl_down(mx, off, 64);
        my += __shfl_down(my, off, 64);
        mz += __shfl_down(mz, off, 64);
    }
    __shared__ float red[4][4];
    const int wave = threadIdx.x >> 6, lane = threadIdx.x & 63;
    if (lane == 0) {
        red[wave][0] = s; red[wave][1] = mx; red[wave][2] = my; red[wave][3] = mz;
    }
    __syncthreads();
    if (threadIdx.x == 0) {
        float a0 = 0.f, a1 = 0.f, a2 = 0.f, a3 = 0.f;
#pragma unroll
        for (int w = 0; w < 4; ++w) {
            a0 += red[w][0]; a1 += red[w][1]; a2 += red[w][2]; a3 += red[w][3];
        }
        float* p = ws + (size_t)bk * (CHUNKS * 4) + chunk * 4;
        p[0] = a0; p[1] = a1; p[2] = a2; p[3] = a3;
    }
}

// out[b,c,v] = sum_k mask[b,k,v] * (M_k g_v + d_k)_c, with per-block
// redundant coefficient construction from the ws partials (L2-broadcast).
__global__ __launch_bounds__(256) void output_kernel(
        const float* __restrict__ mask, const float* __restrict__ ws,
        const float* __restrict__ trans, const float* __restrict__ rot,
        float* __restrict__ out) {
    const int b = blockIdx.y;
    const int tid = threadIdx.x;

    __shared__ float momf[KM1][4];
    __shared__ float cf[KM1 * 12];
    if (tid < KM1 * 4) {
        const int k = tid >> 2, m = tid & 3;
        const float* p = ws + (size_t)(b * KM1 + k) * (CHUNKS * 4) + m;
        float acc = 0.f;
#pragma unroll
        for (int c = 0; c < CHUNKS; ++c) acc += p[c * 4];
        momf[k][m] = acc;
    }
    __syncthreads();
    if (tid < KM1) {
        const int k = tid;
        const int base = b * KM1 + k;
        const float S  = momf[k][0];
        const float p0 = momf[k][1] / S;
        const float p1 = momf[k][2] / S;
        const float p2 = momf[k][3] / S;
        const float* R  = rot + base * 9;
        const float* tv = trans + base * 3;
        float* c = cf + k * 12;
        c[0] = R[0] - 1.0f; c[1] = R[1];        c[2] = R[2];
        c[3] = R[3];        c[4] = R[4] - 1.0f; c[5] = R[5];
        c[6] = R[6];        c[7] = R[7];        c[8] = R[8] - 1.0f;
        c[9]  = p0 - (R[0] * p0 + R[1] * p1 + R[2] * p2) + tv[0];
        c[10] = p1 - (R[3] * p0 + R[4] * p1 + R[5] * p2) + tv[1];
        c[11] = p2 - (R[6] * p0 + R[7] * p1 + R[8] * p2) + tv[2];
    }
    __syncthreads();

    const int v4 = blockIdx.x * 256 + tid;
    const int v = v4 << 2;
    const float gx  = -1.0f + (float)(v >> 12) * GSTEP;
    const float gy  = -1.0f + (float)((v >> 6) & 63) * GSTEP;
    const float gz0 = -1.0f + (float)(v & 63) * GSTEP;
    const float gz1 = gz0 + GSTEP, gz2 = gz0 + 2.f * GSTEP, gz3 = gz0 + 3.f * GSTEP;

    float4 o0 = {0, 0, 0, 0}, o1 = {0, 0, 0, 0}, o2 = {0, 0, 0, 0};
    const float4* m4 = (const float4*)mask + (size_t)b * SK * NV4 + v4;
#pragma unroll
    for (int k = 0; k < KM1; ++k) {
        const float4 m = m4[(size_t)k * NV4];
        const float* c = cf + k * 12;
        const float tx = fmaf(c[0], gx, fmaf(c[1], gy, c[9]));
        const float ty = fmaf(c[3], gx, fmaf(c[4], gy, c[10]));
        const float tz = fmaf(c[6], gx, fmaf(c[7], gy, c[11]));
        o0.x += m.x * fmaf(c[2], gz0, tx);
        o0.y += m.y * fmaf(c[2], gz1, tx);
        o0.z += m.z * fmaf(c[2], gz2, tx);
        o0.w += m.w * fmaf(c[2], gz3, tx);
        o1.x += m.x * fmaf(c[5], gz0, ty);
        o1.y += m.y * fmaf(c[5], gz1, ty);
        o1.z += m.z * fmaf(c[5], gz2, ty);
        o1.w += m.w * fmaf(c[5], gz3, ty);
        o2.x += m.x * fmaf(c[8], gz0, tz);
        o2.y += m.y * fmaf(c[8], gz1, tz);
        o2.z += m.z * fmaf(c[8], gz2, tz);
        o2.w += m.w * fmaf(c[8], gz3, tz);
    }
    // Output is write-once/never-read in this dispatch chain: nontemporal
    // stores keep the L2/L3-warm mask lines from being evicted mid-kernel.
    // (builtin needs a native clang vector type, not HIP_vector_type)
    nt_float4* q0 = (nt_float4*)out + ((size_t)b * 3 + 0) * NV4 + v4;
    nt_float4* q1 = (nt_float4*)out + ((size_t)b * 3 + 1) * NV4 + v4;
    nt_float4* q2 = (nt_float4*)out + ((size_t)b * 3 + 2) * NV4 + v4;
    __builtin_nontemporal_store((nt_float4){o0.x, o0.y, o0.z, o0.w}, q0);
    __builtin_nontemporal_store((nt_float4){o1.x, o1.y, o1.z, o1.w}, q1);
    __builtin_nontemporal_store((nt_float4){o2.x, o2.y, o2.z, o2.w}, q2);
}

extern "C" void kernel_launch(void* const* d_in, const int* in_sizes, int n_in,
                              void* d_out, int out_size, void* d_ws, size_t ws_size,
                              hipStream_t stream) {
    const float* mask  = (const float*)d_in[0]; // (4,8,64,64,64)
    const float* trans = (const float*)d_in[1]; // (4,7,3)
    const float* rot   = (const float*)d_in[2]; // (4,7,3,3)
    float* out = (float*)d_out;                 // (4,3,64,64,64)
    float* ws  = (float*)d_ws;                  // 28*CHUNKS*4 floats of partials

    moments_kernel<<<NBK * CHUNKS, 256, 0, stream>>>(mask, ws);
    output_kernel<<<dim3(NV4 / 256, SB), 256, 0, stream>>>(mask, ws, trans, rot, out);
}